// Round 2
// baseline (325.295 us; speedup 1.0000x reference)
//
#include <hip/hip_runtime.h>

// LocalLayer: y = x @ W^T + b, W banded: output window k (16 outputs)
// reads input cols [16k-32, 16k+32) clamped to [0,4096). Banded GEMM =
// 4.3 GFLOP -> pure memory reshuffle, target is HBM streaming rate.
//
// R2 change vs R1 (92us gemm @ 2.2TB/s, Occ 71% -- occupancy doubling was
// a NO-OP, so not latency-hiding-bound): kill the one-shot stage->barrier->
// compute->exit convoy. Blocks are now long-lived streamers: 32 rows x 8
// window-groups, looping wgs with register-staged double-buffered LDS
// (T14 async-split: issue loads for it+1 before computing it). Loads are
// in flight across barriers; row accesses become temporally contiguous.

typedef __attribute__((ext_vector_type(8))) short short8;
typedef __attribute__((ext_vector_type(4))) float f32x4;
typedef __attribute__((ext_vector_type(4))) unsigned short us4;

#define IN_F 4096
#define OUT_F 4096
#define NROWS 8192
#define ROWS 32                 // batch rows per block
#define GW 16                   // windows per wg (256 output cols)
#define NIT 8                   // wg iterations per block (half the width)
#define WPW 4                   // windows per wave per iteration
#define BAND (GW * 16 + 48)     // 304 input cols covered by one wg band
#define LSTRIDE 312             // LDS row stride (bf16), 16B-aligned
#define V4 (BAND / 4)           // 76 float4 per staged row
#define TOTV4 (ROWS * V4)       // 2432 float4 per band
#define NLD 5                   // ceil(2432/512) load slots per thread

__device__ __forceinline__ unsigned short f2bf(float f) {
  unsigned int u = __float_as_uint(f);
  u += 0x7FFFu + ((u >> 16) & 1u);   // round-to-nearest-even
  return (unsigned short)(u >> 16);
}

// Pack banded W into MFMA B-fragment order, bf16. (unchanged)
// Fragment f = win*2 + t (t = K-half). Lane: n = lane&15, quad = lane>>4,
// k = quad*8 + j. W column = win*16 - 32 + t*32 + k, zero outside [0, IN_F).
__global__ void pack_w_kernel(const float* __restrict__ W,
                              unsigned short* __restrict__ Wp) {
  int tid = blockIdx.x * 256 + threadIdx.x;  // 32768 threads total
  int lane = tid & 63;
  int t = (tid >> 6) & 1;
  int win = tid >> 7;
  int n = lane & 15, quad = lane >> 4;
  int o = win * 16 + n;
  int cbase = win * 16 - 32 + t * 32 + quad * 8;
  short8 h;
#pragma unroll
  for (int j = 0; j < 8; ++j) {
    int c = cbase + j;
    float v = (c >= 0 && c < IN_F) ? W[o * IN_F + c] : 0.0f;
    h[j] = (short)f2bf(v);
  }
  *(short8*)(Wp + (size_t)tid * 8) = h;
}

__global__ __launch_bounds__(512, 4) void local_gemm_kernel(
    const float* __restrict__ x, const unsigned short* __restrict__ Wp,
    const float* __restrict__ bias, float* __restrict__ out) {
  __shared__ unsigned short xs[2][ROWS * LSTRIDE];  // 2 x 19968 B
  const int tid = threadIdx.x;
  const int row0 = blockIdx.x * ROWS;
  const int wgbase = blockIdx.y * NIT;   // y in {0,1}: wgs 0..7 / 8..15

  // Precompute per-thread staging slots (same every iteration).
  int sr[NLD], sc[NLD];
#pragma unroll
  for (int j = 0; j < NLD; ++j) {
    int idx = tid + j * 512;
    sr[j] = idx / V4;
    sc[j] = idx - sr[j] * V4;
  }

  const int lane = tid & 63;
  const int wave = tid >> 6;   // 8 waves
  const int wavem = wave & 1;  // m-tile (16 rows)
  const int wavew = wave >> 1; // window quarter (4 windows)
  const int n16 = lane & 15;
  const int quad = lane >> 4;

  const short8* wpv = (const short8*)Wp;

  float4 ld[NLD];
  // Prologue: issue staging loads for it = 0.
  {
    const int colstart = wgbase * 256 - 32;
#pragma unroll
    for (int j = 0; j < NLD; ++j) {
      float4 v = make_float4(0.f, 0.f, 0.f, 0.f);
      if (tid + j * 512 < TOTV4) {
        int gc = colstart + sc[j] * 4;
        if (gc >= 0 && gc < IN_F)
          v = *(const float4*)(x + (size_t)(row0 + sr[j]) * IN_F + gc);
      }
      ld[j] = v;
    }
  }

  for (int it = 0; it < NIT; ++it) {
    unsigned short* buf = xs[it & 1];
    const int wg = wgbase + it;

    // Convert staged regs -> bf16 LDS (waits vmcnt for ld[] here).
#pragma unroll
    for (int j = 0; j < NLD; ++j) {
      if (tid + j * 512 < TOTV4) {
        us4 h = {f2bf(ld[j].x), f2bf(ld[j].y), f2bf(ld[j].z), f2bf(ld[j].w)};
        *(us4*)(buf + sr[j] * LSTRIDE + sc[j] * 4) = h;
      }
    }
    __syncthreads();   // buf ready for all waves

    // Issue next band's loads NOW -- latency hides under compute+stores.
    if (it + 1 < NIT) {
      const int colstart = (wg + 1) * 256 - 32;
#pragma unroll
      for (int j = 0; j < NLD; ++j) {
        float4 v = make_float4(0.f, 0.f, 0.f, 0.f);
        if (tid + j * 512 < TOTV4) {
          int gc = colstart + sc[j] * 4;
          if (gc >= 0 && gc < IN_F)
            v = *(const float4*)(x + (size_t)(row0 + sr[j]) * IN_F + gc);
        }
        ld[j] = v;
      }
    }

    // Compute: per wave 1 m-tile x 4 windows, 8 MFMA.
    f32x4 acc[WPW];
#pragma unroll
    for (int i = 0; i < WPW; ++i) {
      float bv = bias[wg * 256 + (wavew * WPW + i) * 16 + n16];
      acc[i] = (f32x4){bv, bv, bv, bv};
    }
    const unsigned short* xrow = buf + (wavem * 16 + n16) * LSTRIDE + quad * 8;
#pragma unroll
    for (int i = 0; i < WPW; ++i) {
      int w = wavew * WPW + i;
      int win = wg * GW + w;
      short8 b0 = wpv[(win * 2 + 0) * 64 + lane];  // L2-resident (512 KB)
      short8 b1 = wpv[(win * 2 + 1) * 64 + lane];
      short8 a0 = *(const short8*)(xrow + w * 16);
      short8 a1 = *(const short8*)(xrow + w * 16 + 32);
      acc[i] = __builtin_amdgcn_mfma_f32_16x16x32_bf16(a0, b0, acc[i], 0, 0, 0);
      acc[i] = __builtin_amdgcn_mfma_f32_16x16x32_bf16(a1, b1, acc[i], 0, 0, 0);
    }

    // C/D layout: col = lane&15, row = quad*4 + reg  [m89]
    float* op = out + (size_t)(row0 + wavem * 16 + quad * 4) * OUT_F
              + wg * 256 + n16;
#pragma unroll
    for (int i = 0; i < WPW; ++i) {
#pragma unroll
      for (int r = 0; r < 4; ++r)
        op[r * OUT_F + (wavew * WPW + i) * 16] = acc[i][r];
    }
    __syncthreads();   // all reads of buf done before it+2 overwrites it
  }
}

extern "C" void kernel_launch(void* const* d_in, const int* in_sizes, int n_in,
                              void* d_out, int out_size, void* d_ws, size_t ws_size,
                              hipStream_t stream) {
  const float* x = (const float*)d_in[0];
  const float* W = (const float*)d_in[1];
  const float* b = (const float*)d_in[2];
  // d_in[3] = mask, unused (band structure is compile-time known)
  float* out = (float*)d_out;
  unsigned short* Wp = (unsigned short*)d_ws;  // 256*2*64*8*2 = 512 KB

  hipLaunchKernelGGL(pack_w_kernel, dim3(128), dim3(256), 0, stream, W, Wp);
  hipLaunchKernelGGL(local_gemm_kernel, dim3(NROWS / ROWS, 2), dim3(512),
                     0, stream, x, Wp, b, out);
}

// Round 3
// 304.432 us; speedup vs baseline: 1.0685x; 1.0685x over previous
//
#include <hip/hip_runtime.h>

// LocalLayer: y = x @ W^T + b, W banded: output window k (16 outputs)
// reads input cols [16k-32, 16k+32) clamped to [0,4096). Banded GEMM =
// 4.3 GFLOP -> pure memory reshuffle.
//
// R3 theory: R0-R2 all ran at a CONSTANT ~2.3 TB/s effective HBM BW
// regardless of occupancy (36-71%) and pipelining -> bound by access
// SHAPE, not latency. Suspect: stores straight from MFMA C-fragments are
// 64B segments scattered over 4 rows x 16KB stride (page-thrash). R3
// transposes acc through an LDS out-stage so every store instr is one
// row x 1KB contiguous (global_store_dwordx4), and stores are
// non-temporal so the write stream doesn't evict x from the 256MB L3.

typedef __attribute__((ext_vector_type(8))) short short8;
typedef __attribute__((ext_vector_type(4))) float f32x4;
typedef __attribute__((ext_vector_type(4))) unsigned short us4;

#define IN_F 4096
#define OUT_F 4096
#define NROWS 8192
#define ROWS 32                 // batch rows per block
#define GW 16                   // windows per wg (256 output cols)
#define NIT 8                   // wg iterations per block (half the width)
#define WPW 4                   // windows per wave per iteration
#define BAND (GW * 16 + 48)     // 304 input cols covered by one wg band
#define LSTRIDE 312             // LDS row stride (bf16), 16B-aligned
#define V4 (BAND / 4)           // 76 float4 per staged row
#define TOTV4 (ROWS * V4)       // 2432 float4 per band
#define NLD 5                   // ceil(2432/512) load slots per thread
#define OPAD 260                // out-stage row stride (floats): 16B-aligned, %8==4

__device__ __forceinline__ unsigned short f2bf(float f) {
  unsigned int u = __float_as_uint(f);
  u += 0x7FFFu + ((u >> 16) & 1u);   // round-to-nearest-even
  return (unsigned short)(u >> 16);
}

// Pack banded W into MFMA B-fragment order, bf16. (unchanged)
__global__ void pack_w_kernel(const float* __restrict__ W,
                              unsigned short* __restrict__ Wp) {
  int tid = blockIdx.x * 256 + threadIdx.x;  // 32768 threads total
  int lane = tid & 63;
  int t = (tid >> 6) & 1;
  int win = tid >> 7;
  int n = lane & 15, quad = lane >> 4;
  int o = win * 16 + n;
  int cbase = win * 16 - 32 + t * 32 + quad * 8;
  short8 h;
#pragma unroll
  for (int j = 0; j < 8; ++j) {
    int c = cbase + j;
    float v = (c >= 0 && c < IN_F) ? W[o * IN_F + c] : 0.0f;
    h[j] = (short)f2bf(v);
  }
  *(short8*)(Wp + (size_t)tid * 8) = h;
}

__global__ __launch_bounds__(512, 4) void local_gemm_kernel(
    const float* __restrict__ x, const unsigned short* __restrict__ Wp,
    const float* __restrict__ bias, float* __restrict__ out) {
  __shared__ unsigned short xs[2][ROWS * LSTRIDE];  // 2 x 19968 B
  __shared__ float os[ROWS][OPAD];                  // 33280 B out-stage
  const int tid = threadIdx.x;
  const int row0 = blockIdx.x * ROWS;
  const int wgbase = blockIdx.y * NIT;   // y in {0,1}: wgs 0..7 / 8..15

  // Per-thread staging slots (constant across iterations).
  int sr[NLD], sc[NLD];
#pragma unroll
  for (int j = 0; j < NLD; ++j) {
    int idx = tid + j * 512;
    sr[j] = idx / V4;
    sc[j] = idx - sr[j] * V4;
  }

  const int lane = tid & 63;
  const int wave = tid >> 6;   // 8 waves
  const int wavem = wave & 1;  // m-tile (16 rows)
  const int wavew = wave >> 1; // window quarter (4 windows)
  const int n16 = lane & 15;
  const int quad = lane >> 4;

  const short8* wpv = (const short8*)Wp;

  float4 ld[NLD];
  // Prologue: issue staging loads for it = 0.
  {
    const int colstart = wgbase * 256 - 32;
#pragma unroll
    for (int j = 0; j < NLD; ++j) {
      float4 v = make_float4(0.f, 0.f, 0.f, 0.f);
      if (tid + j * 512 < TOTV4) {
        int gc = colstart + sc[j] * 4;
        if (gc >= 0 && gc < IN_F)
          v = *(const float4*)(x + (size_t)(row0 + sr[j]) * IN_F + gc);
      }
      ld[j] = v;
    }
  }

  for (int it = 0; it < NIT; ++it) {
    unsigned short* buf = xs[it & 1];
    const int wg = wgbase + it;

    // Staged regs -> bf16 LDS.
#pragma unroll
    for (int j = 0; j < NLD; ++j) {
      if (tid + j * 512 < TOTV4) {
        us4 h = {f2bf(ld[j].x), f2bf(ld[j].y), f2bf(ld[j].z), f2bf(ld[j].w)};
        *(us4*)(buf + sr[j] * LSTRIDE + sc[j] * 4) = h;
      }
    }
    __syncthreads();   // (A) buf ready; os from it-1 fully drained

    // Issue next band's loads.
    if (it + 1 < NIT) {
      const int colstart = (wg + 1) * 256 - 32;
#pragma unroll
      for (int j = 0; j < NLD; ++j) {
        float4 v = make_float4(0.f, 0.f, 0.f, 0.f);
        if (tid + j * 512 < TOTV4) {
          int gc = colstart + sc[j] * 4;
          if (gc >= 0 && gc < IN_F)
            v = *(const float4*)(x + (size_t)(row0 + sr[j]) * IN_F + gc);
        }
        ld[j] = v;
      }
    }

    // Compute: per wave 1 m-tile x 4 windows, 8 MFMA.
    f32x4 acc[WPW];
#pragma unroll
    for (int i = 0; i < WPW; ++i) {
      float bv = bias[wg * 256 + (wavew * WPW + i) * 16 + n16];
      acc[i] = (f32x4){bv, bv, bv, bv};
    }
    const unsigned short* xrow = buf + (wavem * 16 + n16) * LSTRIDE + quad * 8;
#pragma unroll
    for (int i = 0; i < WPW; ++i) {
      int w = wavew * WPW + i;
      int win = wg * GW + w;
      short8 b0 = wpv[(win * 2 + 0) * 64 + lane];  // L2-resident (512 KB)
      short8 b1 = wpv[(win * 2 + 1) * 64 + lane];
      short8 a0 = *(const short8*)(xrow + w * 16);
      short8 a1 = *(const short8*)(xrow + w * 16 + 32);
      acc[i] = __builtin_amdgcn_mfma_f32_16x16x32_bf16(a0, b0, acc[i], 0, 0, 0);
      acc[i] = __builtin_amdgcn_mfma_f32_16x16x32_bf16(a1, b1, acc[i], 0, 0, 0);
    }

    // acc -> out-stage. C/D layout: col = lane&15, row = quad*4 + reg [m89].
    // Bank shape: per instr lanes hit 32 distinct banks 2-way -> free.
#pragma unroll
    for (int i = 0; i < WPW; ++i) {
#pragma unroll
      for (int r = 0; r < 4; ++r)
        os[wavem * 16 + quad * 4 + r][(wavew * WPW + i) * 16 + n16] = acc[i][r];
    }
    __syncthreads();   // (B) os complete

    // os -> global: one row = 1KB contiguous per store instr, nt (write-once).
#pragma unroll
    for (int j = 0; j < 4; ++j) {
      int r = wave * 4 + j;
      f32x4 v = *(const f32x4*)(&os[r][lane * 4]);   // linear 1KB ds_read_b128
      __builtin_nontemporal_store(
          v, (f32x4*)(out + (size_t)(row0 + r) * OUT_F + wg * 256 + lane * 4));
    }
  }
}

extern "C" void kernel_launch(void* const* d_in, const int* in_sizes, int n_in,
                              void* d_out, int out_size, void* d_ws, size_t ws_size,
                              hipStream_t stream) {
  const float* x = (const float*)d_in[0];
  const float* W = (const float*)d_in[1];
  const float* b = (const float*)d_in[2];
  // d_in[3] = mask, unused (band structure is compile-time known)
  float* out = (float*)d_out;
  unsigned short* Wp = (unsigned short*)d_ws;  // 256*2*64*8*2 = 512 KB

  hipLaunchKernelGGL(pack_w_kernel, dim3(128), dim3(256), 0, stream, W, Wp);
  hipLaunchKernelGGL(local_gemm_kernel, dim3(NROWS / ROWS, 2), dim3(512),
                     0, stream, x, Wp, b, out);
}

// Round 4
// 302.046 us; speedup vs baseline: 1.0770x; 1.0079x over previous
//
#include <hip/hip_runtime.h>

// LocalLayer: y = x @ W^T + b, W banded: output window k (16 outputs)
// reads input cols [16k-32, 16k+32) clamped to [0,4096). Banded GEMM =
// 4.3 GFLOP -> pure memory reshuffle.
//
// R4 theory: R0-R3 all pinned at ~2.5 TB/s effective BW because hipcc
// drains s_waitcnt vmcnt(0) at every __syncthreads (guide m97). Barrier B
// drained the it+1 prefetch loads (killing the pipeline), barrier A
// drained the store queue (convoying all 8 waves), ~6us of serialized
// drain per ~10.6us iteration. R4: raw s_barrier + manual lgkmcnt(0)
// ONLY (T4: never vmcnt(0) in the loop). LDS hazards need only lgkmcnt;
// prefetch loads get compiler's counted vmcnt at use; nt stores to unique
// addresses are never waited (drained once at s_endpgm).

typedef __attribute__((ext_vector_type(8))) short short8;
typedef __attribute__((ext_vector_type(4))) float f32x4;
typedef __attribute__((ext_vector_type(4))) unsigned short us4;

#define IN_F 4096
#define OUT_F 4096
#define NROWS 8192
#define ROWS 32                 // batch rows per block
#define GW 16                   // windows per wg (256 output cols)
#define NIT 8                   // wg iterations per block (half the width)
#define WPW 4                   // windows per wave per iteration
#define BAND (GW * 16 + 48)     // 304 input cols covered by one wg band
#define LSTRIDE 312             // LDS row stride (bf16), 16B-aligned
#define V4 (BAND / 4)           // 76 float4 per staged row
#define TOTV4 (ROWS * V4)       // 2432 float4 per band
#define NLD 5                   // ceil(2432/512) load slots per thread
#define OPAD 260                // out-stage row stride (floats): 16B-aligned, %8==4

__device__ __forceinline__ unsigned short f2bf(float f) {
  unsigned int u = __float_as_uint(f);
  u += 0x7FFFu + ((u >> 16) & 1u);   // round-to-nearest-even
  return (unsigned short)(u >> 16);
}

// Raw barrier: LDS-drain only, NO vmcnt drain (the whole point of R4).
__device__ __forceinline__ void bar_lgkm() {
  asm volatile("s_waitcnt lgkmcnt(0)" ::: "memory");
  __builtin_amdgcn_sched_barrier(0);
  __builtin_amdgcn_s_barrier();
  __builtin_amdgcn_sched_barrier(0);
}

// Pack banded W into MFMA B-fragment order, bf16. (unchanged)
__global__ void pack_w_kernel(const float* __restrict__ W,
                              unsigned short* __restrict__ Wp) {
  int tid = blockIdx.x * 256 + threadIdx.x;  // 32768 threads total
  int lane = tid & 63;
  int t = (tid >> 6) & 1;
  int win = tid >> 7;
  int n = lane & 15, quad = lane >> 4;
  int o = win * 16 + n;
  int cbase = win * 16 - 32 + t * 32 + quad * 8;
  short8 h;
#pragma unroll
  for (int j = 0; j < 8; ++j) {
    int c = cbase + j;
    float v = (c >= 0 && c < IN_F) ? W[o * IN_F + c] : 0.0f;
    h[j] = (short)f2bf(v);
  }
  *(short8*)(Wp + (size_t)tid * 8) = h;
}

__global__ __launch_bounds__(512, 4) void local_gemm_kernel(
    const float* __restrict__ x, const unsigned short* __restrict__ Wp,
    const float* __restrict__ bias, float* __restrict__ out) {
  __shared__ unsigned short xs[2][ROWS * LSTRIDE];  // 2 x 19968 B
  __shared__ float os[ROWS][OPAD];                  // 33280 B out-stage
  const int tid = threadIdx.x;
  const int row0 = blockIdx.x * ROWS;
  const int wgbase = blockIdx.y * NIT;   // y in {0,1}: wgs 0..7 / 8..15

  // Per-thread staging slots (constant across iterations).
  int sr[NLD], sc[NLD];
#pragma unroll
  for (int j = 0; j < NLD; ++j) {
    int idx = tid + j * 512;
    sr[j] = idx / V4;
    sc[j] = idx - sr[j] * V4;
  }

  const int lane = tid & 63;
  const int wave = tid >> 6;   // 8 waves
  const int wavem = wave & 1;  // m-tile (16 rows)
  const int wavew = wave >> 1; // window quarter (4 windows)
  const int n16 = lane & 15;
  const int quad = lane >> 4;

  const short8* wpv = (const short8*)Wp;

  float4 ld[NLD];
  // Prologue: issue staging loads for it = 0.
  {
    const int colstart = wgbase * 256 - 32;
#pragma unroll
    for (int j = 0; j < NLD; ++j) {
      float4 v = make_float4(0.f, 0.f, 0.f, 0.f);
      if (tid + j * 512 < TOTV4) {
        int gc = colstart + sc[j] * 4;
        if (gc >= 0 && gc < IN_F)
          v = *(const float4*)(x + (size_t)(row0 + sr[j]) * IN_F + gc);
      }
      ld[j] = v;
    }
  }

  for (int it = 0; it < NIT; ++it) {
    unsigned short* buf = xs[it & 1];
    const int wg = wgbase + it;

    // Staged regs -> bf16 LDS. Compiler emits COUNTED vmcnt for ld[] here
    // (loads were issued one full iteration ago -> usually already landed).
#pragma unroll
    for (int j = 0; j < NLD; ++j) {
      if (tid + j * 512 < TOTV4) {
        us4 h = {f2bf(ld[j].x), f2bf(ld[j].y), f2bf(ld[j].z), f2bf(ld[j].w)};
        *(us4*)(buf + sr[j] * LSTRIDE + sc[j] * 4) = h;
      }
    }
    bar_lgkm();   // (A) buf ready for all waves; os from it-1 drained.
                  // No vmcnt drain: it-1 stores + older prefetch stay in flight.

    // Issue next band's loads NOW -- they stay in flight across both
    // barriers, landing before their use at the top of it+1.
    if (it + 1 < NIT) {
      const int colstart = (wg + 1) * 256 - 32;
#pragma unroll
      for (int j = 0; j < NLD; ++j) {
        float4 v = make_float4(0.f, 0.f, 0.f, 0.f);
        if (tid + j * 512 < TOTV4) {
          int gc = colstart + sc[j] * 4;
          if (gc >= 0 && gc < IN_F)
            v = *(const float4*)(x + (size_t)(row0 + sr[j]) * IN_F + gc);
        }
        ld[j] = v;
      }
    }

    // Compute: per wave 1 m-tile x 4 windows, 8 MFMA.
    f32x4 acc[WPW];
#pragma unroll
    for (int i = 0; i < WPW; ++i) {
      float bv = bias[wg * 256 + (wavew * WPW + i) * 16 + n16];
      acc[i] = (f32x4){bv, bv, bv, bv};
    }
    const unsigned short* xrow = buf + (wavem * 16 + n16) * LSTRIDE + quad * 8;
#pragma unroll
    for (int i = 0; i < WPW; ++i) {
      int w = wavew * WPW + i;
      int win = wg * GW + w;
      short8 b0 = wpv[(win * 2 + 0) * 64 + lane];  // L2-resident (512 KB)
      short8 b1 = wpv[(win * 2 + 1) * 64 + lane];
      short8 a0 = *(const short8*)(xrow + w * 16);
      short8 a1 = *(const short8*)(xrow + w * 16 + 32);
      acc[i] = __builtin_amdgcn_mfma_f32_16x16x32_bf16(a0, b0, acc[i], 0, 0, 0);
      acc[i] = __builtin_amdgcn_mfma_f32_16x16x32_bf16(a1, b1, acc[i], 0, 0, 0);
    }

    // acc -> out-stage. C/D layout: col = lane&15, row = quad*4 + reg [m89].
#pragma unroll
    for (int i = 0; i < WPW; ++i) {
#pragma unroll
      for (int r = 0; r < 4; ++r)
        os[wavem * 16 + quad * 4 + r][(wavew * WPW + i) * 16 + n16] = acc[i][r];
    }
    bar_lgkm();   // (B) os complete. Prefetch loads stay in flight!

    // os -> global: one row = 1KB contiguous per store instr, nt.
    // Stores are to unique addresses -> never waited inside the loop.
#pragma unroll
    for (int j = 0; j < 4; ++j) {
      int r = wave * 4 + j;
      f32x4 v = *(const f32x4*)(&os[r][lane * 4]);   // linear 1KB ds_read_b128
      __builtin_nontemporal_store(
          v, (f32x4*)(out + (size_t)(row0 + r) * OUT_F + wg * 256 + lane * 4));
    }
  }
}

extern "C" void kernel_launch(void* const* d_in, const int* in_sizes, int n_in,
                              void* d_out, int out_size, void* d_ws, size_t ws_size,
                              hipStream_t stream) {
  const float* x = (const float*)d_in[0];
  const float* W = (const float*)d_in[1];
  const float* b = (const float*)d_in[2];
  // d_in[3] = mask, unused (band structure is compile-time known)
  float* out = (float*)d_out;
  unsigned short* Wp = (unsigned short*)d_ws;  // 256*2*64*8*2 = 512 KB

  hipLaunchKernelGGL(pack_w_kernel, dim3(128), dim3(256), 0, stream, W, Wp);
  hipLaunchKernelGGL(local_gemm_kernel, dim3(NROWS / ROWS, 2), dim3(512),
                     0, stream, x, Wp, b, out);
}